// Round 8
// baseline (698.939 us; speedup 1.0000x reference)
//
#include <hip/hip_runtime.h>
#include <hip/hip_bf16.h>

using u16 = unsigned short;
typedef __attribute__((ext_vector_type(4))) float f32x4;
typedef __attribute__((ext_vector_type(8))) _Float16 f16x8;
typedef __attribute__((ext_vector_type(4))) unsigned short u16x4;
typedef __attribute__((ext_vector_type(8))) unsigned short u16x8;

#define MFMA(a,b,c) __builtin_amdgcn_mfma_f32_16x16x32_f16((a),(b),(c),0,0,0)

__device__ __forceinline__ u16 f2h(float f){
  _Float16 h = (_Float16)f;
  return __builtin_bit_cast(u16, h);
}
__device__ __forceinline__ float sigm(float x){
  return 1.f / (1.f + __expf(-x));
}
// load 8 consecutive fp32 weights W[row][koff..koff+7], convert to f16x8 fragment
__device__ __forceinline__ f16x8 ldw8(const float* __restrict__ W, int row, int koff){
  const float4* p = (const float4*)(W + row * 128 + koff);
  float4 f0 = p[0], f1 = p[1];
  f16x8 h;
  h[0] = (_Float16)f0.x; h[1] = (_Float16)f0.y; h[2] = (_Float16)f0.z; h[3] = (_Float16)f0.w;
  h[4] = (_Float16)f1.x; h[5] = (_Float16)f1.y; h[6] = (_Float16)f1.z; h[7] = (_Float16)f1.w;
  return h;
}

// ---------------- K1: LN1 + x@[Wproj|Wgate]^T + mask*sigmoid pairing ----------------
// Tile = 128 tokens in a COLUMN of the token matrix: t1 in [k0,k0+128), t2 = j fixed.
// Writes a_r[c][t2][t1], b_r[c][t2][t1] (K-contiguous for K2) via direct per-lane stores.
__launch_bounds__(256, 4)
__global__ void k1_ln_proj(const float* __restrict__ pair, const float* __restrict__ mask,
                           const float* __restrict__ ln1w, const float* __restrict__ ln1b,
                           const float* __restrict__ Wp, const float* __restrict__ Wg,
                           u16* __restrict__ a_r, u16* __restrict__ b_r){
  __shared__ float red_s[128], red_q[128], msk[128];
  __shared__ u16 xs[128 * 136];              // LN1 output fp16, padded stride 136
  int tid = threadIdx.x;
  int bid = blockIdx.x;
  int j   = bid >> 2;
  int k0  = (bid & 3) << 7;

  int cpos = tid & 31;
  int rsub = tid >> 5;
  float4 v[16];
  #pragma unroll
  for (int it = 0; it < 16; ++it){
    int kk = it * 8 + rsub;
    const float4* p = (const float4*)(pair + (((size_t)(k0 + kk) * 512 + j) << 7));
    v[it] = p[cpos];
    float s = v[it].x + v[it].y + v[it].z + v[it].w;
    float q = v[it].x*v[it].x + v[it].y*v[it].y + v[it].z*v[it].z + v[it].w*v[it].w;
    #pragma unroll
    for (int m = 16; m >= 1; m >>= 1){
      s += __shfl_xor(s, m);
      q += __shfl_xor(q, m);
    }
    if (cpos == 0){ red_s[kk] = s; red_q[kk] = q; }
  }
  if (tid < 128) msk[tid] = mask[(size_t)(k0 + tid) * 512 + j];
  __syncthreads();

  float4 w4 = ((const float4*)ln1w)[cpos];
  float4 b4 = ((const float4*)ln1b)[cpos];
  #pragma unroll
  for (int it = 0; it < 16; ++it){
    int kk = it * 8 + rsub;
    float mu = red_s[kk] * (1.f / 128.f);
    float var = red_q[kk] * (1.f / 128.f) - mu * mu;
    float rs = rsqrtf(var + 1e-5f);
    u16x4 o;
    o[0] = f2h((v[it].x - mu) * rs * w4.x + b4.x);
    o[1] = f2h((v[it].y - mu) * rs * w4.y + b4.y);
    o[2] = f2h((v[it].z - mu) * rs * w4.z + b4.z);
    o[3] = f2h((v[it].w - mu) * rs * w4.w + b4.w);
    *(u16x4*)&xs[kk * 136 + cpos * 4] = o;
  }
  __syncthreads();

  int lane = tid & 63;
  int wv   = tid >> 6;
  int l15  = lane & 15;
  int l4   = lane >> 4;

  #pragma unroll
  for (int pi = 0; pi < 4; ++pi){
    int tp = pi * 4 + wv;
    int nP = tp * 16 + l15;
    f32x4 accP[8] = {}; f32x4 accG[8] = {};
    #pragma unroll
    for (int ks = 0; ks < 4; ++ks){
      f16x8 bP = ldw8(Wp, nP, ks * 32 + l4 * 8);
      f16x8 bG = ldw8(Wg, nP, ks * 32 + l4 * 8);
      #pragma unroll
      for (int mi = 0; mi < 8; ++mi){
        f16x8 af = *(const f16x8*)&xs[(mi * 16 + l15) * 136 + ks * 32 + l4 * 8];
        accP[mi] = MFMA(af, bP, accP[mi]);
        accG[mi] = MFMA(af, bG, accG[mi]);
      }
    }
    // epilogue: direct per-lane stores (lane owns col nP, tokens m0..m0+3 contiguous)
    int c = nP >> 1;
    u16* dst = (nP & 1) ? b_r : a_r;
    size_t base = ((size_t)c * 512 + j) * 512 + k0;
    #pragma unroll
    for (int mi = 0; mi < 8; ++mi){
      int m0 = mi * 16 + l4 * 4;
      u16x4 o;
      #pragma unroll
      for (int r = 0; r < 4; ++r){
        float p = accP[mi][r] * msk[m0 + r] * sigm(accG[mi][r]);
        o[r] = f2h(p);
      }
      *(u16x4*)&dst[base + m0] = o;
    }
  }
}

// ---------------- K2: triangle einsum, 128 per-channel 512x512x512 fp16 GEMMs ----------------
__launch_bounds__(256, 2)
__global__ void k2_tri(const u16* __restrict__ a_r, const u16* __restrict__ b_r,
                       float* __restrict__ o_f){
  int tid = threadIdx.x;
  int p = blockIdx.x;
  int lb = (p & 7) * 256 + (p >> 3);         // bijective: 2048 = 8 * 256
  int c  = lb >> 4;
  int t  = lb & 15;
  int lane = tid & 63, wv = tid >> 6;
  int i0 = (t >> 2) * 128 + (wv >> 1) * 64;
  int j0 = (t & 3) * 128 + (wv & 1) * 64;
  int l15 = lane & 15, l4 = lane >> 4;
  const u16* pa = a_r + (size_t)c * 262144;
  const u16* pb = b_r + (size_t)c * 262144;

  f32x4 acc[4][4] = {};
  for (int ks = 0; ks < 16; ++ks){
    f16x8 A[4], B[4];
    #pragma unroll
    for (int ai = 0; ai < 4; ++ai)
      A[ai] = *(const f16x8*)&pb[(i0 + ai * 16 + l15) * 512 + ks * 32 + l4 * 8];
    #pragma unroll
    for (int bj = 0; bj < 4; ++bj)
      B[bj] = *(const f16x8*)&pa[(j0 + bj * 16 + l15) * 512 + ks * 32 + l4 * 8];
    #pragma unroll
    for (int ai = 0; ai < 4; ++ai)
      #pragma unroll
      for (int bj = 0; bj < 4; ++bj)
        acc[ai][bj] = MFMA(A[ai], B[bj], acc[ai][bj]);
  }
  float* po = o_f + (size_t)c * 262144;
  #pragma unroll
  for (int ai = 0; ai < 4; ++ai){
    #pragma unroll
    for (int r = 0; r < 4; ++r){
      int i = i0 + ai * 16 + l4 * 4 + r;
      #pragma unroll
      for (int bj = 0; bj < 4; ++bj)
        po[i * 512 + j0 + bj * 16 + l15] = acc[ai][bj][r];
    }
  }
}

// ---------------- K2b: LN2 over o_f + transpose -> x2g[t][ci] fp16 ----------------
// Thread owns 8 CONSECUTIVE channels (ci = grp*8 + it) -> vectorized u16x8 LDS stores.
__launch_bounds__(256, 6)
__global__ void k2b_lnt(const float* __restrict__ o_f,
                        const float* __restrict__ ln2w, const float* __restrict__ ln2b,
                        u16* __restrict__ x2g){
  __shared__ float sred[2][4][16][4];        // [s|q][wave][part][r]
  __shared__ float mu_s[64], rs_s[64];
  __shared__ u16 tr2[64 * 136];              // [t_local][ci], stride 136 (16B-aligned rows)
  int tid = threadIdx.x;
  size_t t0 = (size_t)blockIdx.x * 64;
  int part = tid & 15;                       // t-quad index
  int grp  = tid >> 4;                       // ci-octet 0..15
  int ci0  = grp * 8;
  int wv = tid >> 6, lane = tid & 63;

  f32x4 vals[8];
  float s4[4] = {0,0,0,0}, q4[4] = {0,0,0,0};
  #pragma unroll
  for (int it = 0; it < 8; ++it){
    vals[it] = *(const f32x4*)&o_f[(size_t)(ci0 + it) * 262144 + t0 + part * 4];
    #pragma unroll
    for (int r = 0; r < 4; ++r){ s4[r] += vals[it][r]; q4[r] += vals[it][r]*vals[it][r]; }
  }
  #pragma unroll
  for (int r = 0; r < 4; ++r){
    s4[r] += __shfl_xor(s4[r], 16); q4[r] += __shfl_xor(q4[r], 16);
    s4[r] += __shfl_xor(s4[r], 32); q4[r] += __shfl_xor(q4[r], 32);
  }
  if (lane < 16){
    #pragma unroll
    for (int r = 0; r < 4; ++r){ sred[0][wv][lane][r] = s4[r]; sred[1][wv][lane][r] = q4[r]; }
  }
  __syncthreads();
  if (tid < 64){
    float s = 0.f, q = 0.f;
    #pragma unroll
    for (int w = 0; w < 4; ++w){ s += sred[0][w][tid >> 2][tid & 3]; q += sred[1][w][tid >> 2][tid & 3]; }
    float mu = s * (1.f / 128.f);
    float var = q * (1.f / 128.f) - mu * mu;
    mu_s[tid] = mu;
    rs_s[tid] = rsqrtf(var + 1e-5f);
  }
  __syncthreads();
  {
    float4 w2a = *(const float4*)(ln2w + ci0);
    float4 w2b = *(const float4*)(ln2w + ci0 + 4);
    float4 b2a = *(const float4*)(ln2b + ci0);
    float4 b2b = *(const float4*)(ln2b + ci0 + 4);
    float w2[8] = {w2a.x,w2a.y,w2a.z,w2a.w,w2b.x,w2b.y,w2b.z,w2b.w};
    float b2[8] = {b2a.x,b2a.y,b2a.z,b2a.w,b2b.x,b2b.y,b2b.z,b2b.w};
    #pragma unroll
    for (int r = 0; r < 4; ++r){
      int tl = part * 4 + r;
      float mu = mu_s[tl], rs = rs_s[tl];
      u16x8 o;
      #pragma unroll
      for (int it = 0; it < 8; ++it)
        o[it] = f2h((vals[it][r] - mu) * rs * w2[it] + b2[it]);
      *(u16x8*)&tr2[tl * 136 + ci0] = o;
    }
  }
  __syncthreads();
  // flush: 16B coalesced global stores
  #pragma unroll
  for (int it = 0; it < 4; ++it){
    int flat = it * 256 + tid;
    int t = flat >> 4, ch = flat & 15;
    u16x8 o = *(const u16x8*)&tr2[t * 136 + ch * 8];
    *(u16x8*)&x2g[(t0 + t) * 128 + ch * 8] = o;
  }
}

// ---------------- K3: barrier-free dual GEMM ----------------
// out = (LN2'd x2g)@Wo^T * sigm( rs*(fp16(pair)@(w1*Wgl)^T - mu*S) + B )
// LN1 stats and S,B accumulated in-loop from the fragment loads themselves.
__launch_bounds__(256, 3)
__global__ void k3_out(const u16* __restrict__ x2g, const float* __restrict__ pair,
                       const float* __restrict__ ln1w, const float* __restrict__ ln1b,
                       const float* __restrict__ Wgl, const float* __restrict__ Wo,
                       float* __restrict__ out){
  int tid = threadIdx.x, bid = blockIdx.x;
  int i  = bid >> 3;                         // output row index
  int j0 = (bid & 7) << 6;                   // 64-token j block
  int lane = tid & 63, wv = tid >> 6;
  int l15 = lane & 15, l4 = lane >> 4;
  int n0 = wv * 32;

  f32x4 accO[4][2] = {};
  f32x4 accG[4][2] = {};
  float sA[4] = {0,0,0,0}, qA[4] = {0,0,0,0};
  float sS0 = 0.f, sS1 = 0.f, sB0 = 0.f, sB1 = 0.f;

  #pragma unroll
  for (int ks = 0; ks < 4; ++ks){
    int koff = ks * 32 + l4 * 8;
    float4 w1a = *(const float4*)(ln1w + koff);
    float4 w1b = *(const float4*)(ln1w + koff + 4);
    float4 b1a = *(const float4*)(ln1b + koff);
    float4 b1b = *(const float4*)(ln1b + koff + 4);

    f16x8 G0, G1;
    {
      const float4* p = (const float4*)(Wgl + (n0 + l15) * 128 + koff);
      float4 f0 = p[0], f1 = p[1];
      float e0=f0.x*w1a.x, e1=f0.y*w1a.y, e2=f0.z*w1a.z, e3=f0.w*w1a.w;
      float e4=f1.x*w1b.x, e5=f1.y*w1b.y, e6=f1.z*w1b.z, e7=f1.w*w1b.w;
      G0[0]=(_Float16)e0; G0[1]=(_Float16)e1; G0[2]=(_Float16)e2; G0[3]=(_Float16)e3;
      G0[4]=(_Float16)e4; G0[5]=(_Float16)e5; G0[6]=(_Float16)e6; G0[7]=(_Float16)e7;
      sS0 += (e0+e1+e2+e3)+(e4+e5+e6+e7);
      sB0 += f0.x*b1a.x + f0.y*b1a.y + f0.z*b1a.z + f0.w*b1a.w
           + f1.x*b1b.x + f1.y*b1b.y + f1.z*b1b.z + f1.w*b1b.w;
    }
    {
      const float4* p = (const float4*)(Wgl + (n0 + 16 + l15) * 128 + koff);
      float4 f0 = p[0], f1 = p[1];
      float e0=f0.x*w1a.x, e1=f0.y*w1a.y, e2=f0.z*w1a.z, e3=f0.w*w1a.w;
      float e4=f1.x*w1b.x, e5=f1.y*w1b.y, e6=f1.z*w1b.z, e7=f1.w*w1b.w;
      G1[0]=(_Float16)e0; G1[1]=(_Float16)e1; G1[2]=(_Float16)e2; G1[3]=(_Float16)e3;
      G1[4]=(_Float16)e4; G1[5]=(_Float16)e5; G1[6]=(_Float16)e6; G1[7]=(_Float16)e7;
      sS1 += (e0+e1+e2+e3)+(e4+e5+e6+e7);
      sB1 += f0.x*b1a.x + f0.y*b1a.y + f0.z*b1a.z + f0.w*b1a.w
           + f1.x*b1b.x + f1.y*b1b.y + f1.z*b1b.z + f1.w*b1b.w;
    }
    f16x8 B0 = ldw8(Wo, n0 + l15, koff);
    f16x8 B1 = ldw8(Wo, n0 + 16 + l15, koff);

    #pragma unroll
    for (int mi = 0; mi < 4; ++mi){
      size_t row = (size_t)i * 512 + j0 + mi * 16 + l15;
      f16x8 A2 = *(const f16x8*)&x2g[row * 128 + koff];
      const float4* pp = (const float4*)(pair + row * 128 + koff);
      float4 x0 = pp[0], x1 = pp[1];
      f16x8 A1;
      A1[0]=(_Float16)x0.x; A1[1]=(_Float16)x0.y; A1[2]=(_Float16)x0.z; A1[3]=(_Float16)x0.w;
      A1[4]=(_Float16)x1.x; A1[5]=(_Float16)x1.y; A1[6]=(_Float16)x1.z; A1[7]=(_Float16)x1.w;
      sA[mi] += (x0.x+x0.y+x0.z+x0.w) + (x1.x+x1.y+x1.z+x1.w);
      qA[mi] += x0.x*x0.x + x0.y*x0.y + x0.z*x0.z + x0.w*x0.w
              + x1.x*x1.x + x1.y*x1.y + x1.z*x1.z + x1.w*x1.w;
      accO[mi][0] = MFMA(A2, B0, accO[mi][0]);
      accO[mi][1] = MFMA(A2, B1, accO[mi][1]);
      accG[mi][0] = MFMA(A1, G0, accG[mi][0]);
      accG[mi][1] = MFMA(A1, G1, accG[mi][1]);
    }
  }

  // reduce stats across the 4 l4-groups (lanes sharing l15)
  #pragma unroll
  for (int mi = 0; mi < 4; ++mi){
    sA[mi] += __shfl_xor(sA[mi], 16); sA[mi] += __shfl_xor(sA[mi], 32);
    qA[mi] += __shfl_xor(qA[mi], 16); qA[mi] += __shfl_xor(qA[mi], 32);
  }
  sS0 += __shfl_xor(sS0, 16); sS0 += __shfl_xor(sS0, 32);
  sS1 += __shfl_xor(sS1, 16); sS1 += __shfl_xor(sS1, 32);
  sB0 += __shfl_xor(sB0, 16); sB0 += __shfl_xor(sB0, 32);
  sB1 += __shfl_xor(sB1, 16); sB1 += __shfl_xor(sB1, 32);

  #pragma unroll
  for (int mi = 0; mi < 4; ++mi){
    float mu_r = sA[mi] * (1.f / 128.f);                 // stats of row mi*16 + l15
    float rs_r = rsqrtf(qA[mi] * (1.f / 128.f) - mu_r * mu_r + 1e-5f);
    #pragma unroll
    for (int r = 0; r < 4; ++r){
      int srcl = (lane & 48) | (l4 * 4 + r);             // lane holding stats of C-row
      float mu = __shfl(mu_r, srcl);
      float rs = __shfl(rs_r, srcl);
      int m = mi * 16 + l4 * 4 + r;
      size_t tok = (size_t)i * 512 + j0 + m;
      float g0 = rs * (accG[mi][0][r] - mu * sS0) + sB0;
      float g1 = rs * (accG[mi][1][r] - mu * sS1) + sB1;
      out[tok * 128 + n0 + l15]      = accO[mi][0][r] * sigm(g0);
      out[tok * 128 + n0 + 16 + l15] = accO[mi][1][r] * sigm(g1);
    }
  }
}

extern "C" void kernel_launch(void* const* d_in, const int* in_sizes, int n_in,
                              void* d_out, int out_size, void* d_ws, size_t ws_size,
                              hipStream_t stream){
  (void)in_sizes; (void)n_in; (void)out_size; (void)ws_size;
  const float* pair = (const float*)d_in[0];
  const float* mask = (const float*)d_in[1];
  const float* ln1w = (const float*)d_in[2];
  const float* ln1b = (const float*)d_in[3];
  const float* ln2w = (const float*)d_in[4];
  const float* ln2b = (const float*)d_in[5];
  const float* Wp   = (const float*)d_in[6];
  const float* Wg   = (const float*)d_in[7];
  const float* Wo   = (const float*)d_in[8];   // W_out comes BEFORE W_glin in dict order
  const float* Wgl  = (const float*)d_in[9];
  float* out = (float*)d_out;

  // Workspace: exactly 256 MiB. x2g aliases a_r (dead after k2; fully rewritten
  // by k1 at the start of every call -> deterministic across graph replays).
  char* ws = (char*)d_ws;
  u16*   a_r = (u16*)(ws);                       // 67108864 B   a_r[c][j][k]  fp16
  u16*   b_r = (u16*)(ws + 67108864);            // 67108864 B   b_r[c][i][k]  fp16
  float* o_f = (float*)(ws + 134217728);         // 134217728 B  o_f[c][i][j]  fp32
  u16*   x2g = (u16*)(ws);                       // 67108864 B   x2g[t][ci]    fp16 (aliases a_r)

  hipLaunchKernelGGL(k1_ln_proj, dim3(2048), dim3(256), 0, stream, pair, mask, ln1w, ln1b, Wp, Wg, a_r, b_r);
  hipLaunchKernelGGL(k2_tri,     dim3(2048), dim3(256), 0, stream, a_r, b_r, o_f);
  hipLaunchKernelGGL(k2b_lnt,    dim3(4096), dim3(256), 0, stream, o_f, ln2w, ln2b, x2g);
  hipLaunchKernelGGL(k3_out,     dim3(4096), dim3(256), 0, stream, x2g, pair, ln1w, ln1b, Wgl, Wo, out);
}

// Round 10
// 432.175 us; speedup vs baseline: 1.6173x; 1.6173x over previous
//
#include <hip/hip_runtime.h>
#include <hip/hip_bf16.h>

using u16 = unsigned short;
typedef __attribute__((ext_vector_type(4))) float f32x4;
typedef __attribute__((ext_vector_type(8))) _Float16 f16x8;
typedef __attribute__((ext_vector_type(4))) unsigned short u16x4;
typedef __attribute__((ext_vector_type(8))) unsigned short u16x8;

#define MFMA(a,b,c) __builtin_amdgcn_mfma_f32_16x16x32_f16((a),(b),(c),0,0,0)

__device__ __forceinline__ u16 f2h(float f){
  _Float16 h = (_Float16)f;
  return __builtin_bit_cast(u16, h);
}
__device__ __forceinline__ float sigm(float x){
  return 1.f / (1.f + __expf(-x));
}
// load 8 consecutive fp32 weights W[row][koff..koff+7], convert to f16x8 fragment
__device__ __forceinline__ f16x8 ldw8(const float* __restrict__ W, int row, int koff){
  const float4* p = (const float4*)(W + row * 128 + koff);
  float4 f0 = p[0], f1 = p[1];
  f16x8 h;
  h[0] = (_Float16)f0.x; h[1] = (_Float16)f0.y; h[2] = (_Float16)f0.z; h[3] = (_Float16)f0.w;
  h[4] = (_Float16)f1.x; h[5] = (_Float16)f1.y; h[6] = (_Float16)f1.z; h[7] = (_Float16)f1.w;
  return h;
}

// ---------------- K0: pre-convert [Wproj;Wgate] fp32 -> fp16 into Wc (aliases o_f head) ----------------
__global__ void k0_prep(const float* __restrict__ Wp, const float* __restrict__ Wg,
                        u16* __restrict__ Wc){
  int idx = blockIdx.x * 256 + threadIdx.x;   // grid covers 512*128 exactly
  int n = idx >> 7, k = idx & 127;
  float v = (n < 256) ? Wp[n * 128 + k] : Wg[(n - 256) * 128 + k];
  Wc[idx] = f2h(v);
}

// ---------------- K1: LN1 + x@[Wproj|Wgate]^T + mask*sigmoid pairing ----------------
// (R7-proven structure; weights now pre-converted fp16 from Wc)
__launch_bounds__(256, 3)
__global__ void k1_ln_proj(const float* __restrict__ pair, const float* __restrict__ mask,
                           const float* __restrict__ ln1w, const float* __restrict__ ln1b,
                           const u16* __restrict__ Wc,
                           u16* __restrict__ a_r, u16* __restrict__ b_r){
  __shared__ float red_s[128], red_q[128], msk[128];
  __shared__ u16 xs[128 * 136];              // LN1 output fp16, padded stride 136
  __shared__ u16 sbuf[4][16 * 132];          // per-wave a/b staging
  int tid = threadIdx.x;
  int bid = blockIdx.x;
  int j   = bid >> 2;
  int k0  = (bid & 3) << 7;

  int cpos = tid & 31;
  int rsub = tid >> 5;
  float4 v[16];
  #pragma unroll
  for (int it = 0; it < 16; ++it){
    int kk = it * 8 + rsub;
    const float4* p = (const float4*)(pair + (((size_t)(k0 + kk) * 512 + j) << 7));
    v[it] = p[cpos];
    float s = v[it].x + v[it].y + v[it].z + v[it].w;
    float q = v[it].x*v[it].x + v[it].y*v[it].y + v[it].z*v[it].z + v[it].w*v[it].w;
    #pragma unroll
    for (int m = 16; m >= 1; m >>= 1){
      s += __shfl_xor(s, m);
      q += __shfl_xor(q, m);
    }
    if (cpos == 0){ red_s[kk] = s; red_q[kk] = q; }
  }
  if (tid < 128) msk[tid] = mask[(size_t)(k0 + tid) * 512 + j];
  __syncthreads();

  float4 w4 = ((const float4*)ln1w)[cpos];
  float4 b4 = ((const float4*)ln1b)[cpos];
  #pragma unroll
  for (int it = 0; it < 16; ++it){
    int kk = it * 8 + rsub;
    float mu = red_s[kk] * (1.f / 128.f);
    float var = red_q[kk] * (1.f / 128.f) - mu * mu;
    float rs = rsqrtf(var + 1e-5f);
    u16x4 o;
    o[0] = f2h((v[it].x - mu) * rs * w4.x + b4.x);
    o[1] = f2h((v[it].y - mu) * rs * w4.y + b4.y);
    o[2] = f2h((v[it].z - mu) * rs * w4.z + b4.z);
    o[3] = f2h((v[it].w - mu) * rs * w4.w + b4.w);
    *(u16x4*)&xs[kk * 136 + cpos * 4] = o;
  }
  __syncthreads();

  int lane = tid & 63;
  int wv   = tid >> 6;
  int l15  = lane & 15;
  int l4   = lane >> 4;
  u16* sb  = sbuf[wv];

  #pragma unroll
  for (int pi = 0; pi < 4; ++pi){
    int tp = pi * 4 + wv;
    int nP = tp * 16 + l15;
    f32x4 accP[8] = {}; f32x4 accG[8] = {};
    #pragma unroll
    for (int ks = 0; ks < 4; ++ks){
      f16x8 bP = *(const f16x8*)&Wc[nP * 128 + ks * 32 + l4 * 8];
      f16x8 bG = *(const f16x8*)&Wc[(256 + nP) * 128 + ks * 32 + l4 * 8];
      #pragma unroll
      for (int mi = 0; mi < 8; ++mi){
        f16x8 af = *(const f16x8*)&xs[(mi * 16 + l15) * 136 + ks * 32 + l4 * 8];
        accP[mi] = MFMA(af, bP, accP[mi]);
        accG[mi] = MFMA(af, bG, accG[mi]);
      }
    }
    #pragma unroll
    for (int mi = 0; mi < 8; ++mi){
      int m0 = mi * 16 + l4 * 4;
      u16x4 o;
      #pragma unroll
      for (int r = 0; r < 4; ++r){
        float p = accP[mi][r] * msk[m0 + r] * sigm(accG[mi][r]);
        o[r] = f2h(p);
      }
      *(u16x4*)&sb[l15 * 132 + m0] = o;
    }
    #pragma unroll
    for (int r2 = 0; r2 < 8; ++r2){
      int row = r2 * 2 + (lane >> 5);
      int col = (lane & 31) * 4;
      u16x4 vv = *(const u16x4*)&sb[row * 132 + col];
      int nP2 = tp * 16 + row;
      int c = nP2 >> 1;
      u16* dst = (nP2 & 1) ? b_r : a_r;
      *(u16x4*)&dst[((size_t)c * 512 + j) * 512 + k0 + col] = vv;
    }
  }
}

// ---------------- K2: triangle einsum, 128 per-channel 512x512x512 fp16 GEMMs ----------------
__launch_bounds__(256, 2)
__global__ void k2_tri(const u16* __restrict__ a_r, const u16* __restrict__ b_r,
                       float* __restrict__ o_f){
  int tid = threadIdx.x;
  int p = blockIdx.x;
  int lb = (p & 7) * 256 + (p >> 3);         // bijective: 2048 = 8 * 256
  int c  = lb >> 4;
  int t  = lb & 15;
  int lane = tid & 63, wv = tid >> 6;
  int i0 = (t >> 2) * 128 + (wv >> 1) * 64;
  int j0 = (t & 3) * 128 + (wv & 1) * 64;
  int l15 = lane & 15, l4 = lane >> 4;
  const u16* pa = a_r + (size_t)c * 262144;
  const u16* pb = b_r + (size_t)c * 262144;

  f32x4 acc[4][4] = {};
  for (int ks = 0; ks < 16; ++ks){
    f16x8 A[4], B[4];
    #pragma unroll
    for (int ai = 0; ai < 4; ++ai)
      A[ai] = *(const f16x8*)&pb[(i0 + ai * 16 + l15) * 512 + ks * 32 + l4 * 8];
    #pragma unroll
    for (int bj = 0; bj < 4; ++bj)
      B[bj] = *(const f16x8*)&pa[(j0 + bj * 16 + l15) * 512 + ks * 32 + l4 * 8];
    #pragma unroll
    for (int ai = 0; ai < 4; ++ai)
      #pragma unroll
      for (int bj = 0; bj < 4; ++bj)
        acc[ai][bj] = MFMA(A[ai], B[bj], acc[ai][bj]);
  }
  float* po = o_f + (size_t)c * 262144;
  #pragma unroll
  for (int ai = 0; ai < 4; ++ai){
    #pragma unroll
    for (int r = 0; r < 4; ++r){
      int i = i0 + ai * 16 + l4 * 4 + r;
      #pragma unroll
      for (int bj = 0; bj < 4; ++bj)
        po[i * 512 + j0 + bj * 16 + l15] = acc[ai][bj][r];
    }
  }
}

// ---------------- K2b: LN2 over o_f + transpose -> x2g[t][ci] fp16 (R8-validated) ----------------
__launch_bounds__(256, 6)
__global__ void k2b_lnt(const float* __restrict__ o_f,
                        const float* __restrict__ ln2w, const float* __restrict__ ln2b,
                        u16* __restrict__ x2g){
  __shared__ float sred[2][4][16][4];        // [s|q][wave][part][r]
  __shared__ float mu_s[64], rs_s[64];
  __shared__ u16 tr2[64 * 136];              // [t_local][ci], stride 136
  int tid = threadIdx.x;
  size_t t0 = (size_t)blockIdx.x * 64;
  int part = tid & 15;                       // t-quad index
  int grp  = tid >> 4;                       // ci-octet 0..15
  int ci0  = grp * 8;
  int wv = tid >> 6, lane = tid & 63;

  f32x4 vals[8];
  float s4[4] = {0,0,0,0}, q4[4] = {0,0,0,0};
  #pragma unroll
  for (int it = 0; it < 8; ++it){
    vals[it] = *(const f32x4*)&o_f[(size_t)(ci0 + it) * 262144 + t0 + part * 4];
    #pragma unroll
    for (int r = 0; r < 4; ++r){ s4[r] += vals[it][r]; q4[r] += vals[it][r]*vals[it][r]; }
  }
  #pragma unroll
  for (int r = 0; r < 4; ++r){
    s4[r] += __shfl_xor(s4[r], 16); q4[r] += __shfl_xor(q4[r], 16);
    s4[r] += __shfl_xor(s4[r], 32); q4[r] += __shfl_xor(q4[r], 32);
  }
  if (lane < 16){
    #pragma unroll
    for (int r = 0; r < 4; ++r){ sred[0][wv][lane][r] = s4[r]; sred[1][wv][lane][r] = q4[r]; }
  }
  __syncthreads();
  if (tid < 64){
    float s = 0.f, q = 0.f;
    #pragma unroll
    for (int w = 0; w < 4; ++w){ s += sred[0][w][tid >> 2][tid & 3]; q += sred[1][w][tid >> 2][tid & 3]; }
    float mu = s * (1.f / 128.f);
    float var = q * (1.f / 128.f) - mu * mu;
    mu_s[tid] = mu;
    rs_s[tid] = rsqrtf(var + 1e-5f);
  }
  __syncthreads();
  {
    float4 w2a = *(const float4*)(ln2w + ci0);
    float4 w2b = *(const float4*)(ln2w + ci0 + 4);
    float4 b2a = *(const float4*)(ln2b + ci0);
    float4 b2b = *(const float4*)(ln2b + ci0 + 4);
    float w2[8] = {w2a.x,w2a.y,w2a.z,w2a.w,w2b.x,w2b.y,w2b.z,w2b.w};
    float b2[8] = {b2a.x,b2a.y,b2a.z,b2a.w,b2b.x,b2b.y,b2b.z,b2b.w};
    #pragma unroll
    for (int r = 0; r < 4; ++r){
      int tl = part * 4 + r;
      float mu = mu_s[tl], rs = rs_s[tl];
      u16x8 o;
      #pragma unroll
      for (int it = 0; it < 8; ++it)
        o[it] = f2h((vals[it][r] - mu) * rs * w2[it] + b2[it]);
      *(u16x8*)&tr2[tl * 136 + ci0] = o;
    }
  }
  __syncthreads();
  #pragma unroll
  for (int it = 0; it < 4; ++it){
    int flat = it * 256 + tid;
    int t = flat >> 4, ch = flat & 15;
    u16x8 o = *(const u16x8*)&tr2[t * 136 + ch * 8];
    *(u16x8*)&x2g[(t0 + t) * 128 + ch * 8] = o;
  }
}

// ---------------- K3: LN1(pair)@W_glin gate + x2g@W_out^T -> out (R7-validated, verbatim) ----------------
__launch_bounds__(256, 4)
__global__ void k3_out(const u16* __restrict__ x2g, const float* __restrict__ pair,
                       const float* __restrict__ ln1w, const float* __restrict__ ln1b,
                       const float* __restrict__ Wgl, const float* __restrict__ Wo,
                       float* __restrict__ out){
  __shared__ u16 x1[64 * 136];               // LN1(pair) fp16 [jj][cin]
  __shared__ float r1s[64], r1q[64];
  int tid = threadIdx.x, bid = blockIdx.x;
  int i  = bid >> 3;                         // output row index
  int j0 = (bid & 7) << 6;                   // 64-token j block

  // Phase A: LN1 over pair rows (i, j0+jj)
  int cq = tid & 31, jsub = tid >> 5;
  float4 pv[8];
  #pragma unroll
  for (int it = 0; it < 8; ++it){
    int jj = it * 8 + jsub;
    const float4* p = (const float4*)(pair + (((size_t)i * 512 + j0 + jj) << 7));
    pv[it] = p[cq];
    float s = pv[it].x + pv[it].y + pv[it].z + pv[it].w;
    float q = pv[it].x*pv[it].x + pv[it].y*pv[it].y + pv[it].z*pv[it].z + pv[it].w*pv[it].w;
    #pragma unroll
    for (int m = 16; m >= 1; m >>= 1){
      s += __shfl_xor(s, m);
      q += __shfl_xor(q, m);
    }
    if (cq == 0){ r1s[jj] = s; r1q[jj] = q; }
  }
  __syncthreads();
  {
    float4 w1 = ((const float4*)ln1w)[cq];
    float4 b1 = ((const float4*)ln1b)[cq];
    #pragma unroll
    for (int it = 0; it < 8; ++it){
      int jj = it * 8 + jsub;
      float mu = r1s[jj] * (1.f / 128.f);
      float var = r1q[jj] * (1.f / 128.f) - mu * mu;
      float rs = rsqrtf(var + 1e-5f);
      u16x4 o;
      o[0] = f2h((pv[it].x - mu) * rs * w1.x + b1.x);
      o[1] = f2h((pv[it].y - mu) * rs * w1.y + b1.y);
      o[2] = f2h((pv[it].z - mu) * rs * w1.z + b1.z);
      o[3] = f2h((pv[it].w - mu) * rs * w1.w + b1.w);
      *(u16x4*)&x1[jj * 136 + cq * 4] = o;
    }
  }
  __syncthreads();

  // Phase B: dual GEMM. A2 from global x2g, A1 from LDS x1.
  int lane = tid & 63, wv = tid >> 6;
  int l15 = lane & 15, l4 = lane >> 4;
  int n0 = wv * 32;
  f32x4 accO[4][2] = {};
  f32x4 accG[4][2] = {};
  #pragma unroll
  for (int ks = 0; ks < 4; ++ks){
    int koff = ks * 32 + l4 * 8;
    f16x8 B0 = ldw8(Wo, n0 + l15, koff);
    f16x8 B1 = ldw8(Wo, n0 + 16 + l15, koff);
    f16x8 G0 = ldw8(Wgl, n0 + l15, koff);
    f16x8 G1 = ldw8(Wgl, n0 + 16 + l15, koff);
    #pragma unroll
    for (int mi = 0; mi < 4; ++mi){
      f16x8 A2 = *(const f16x8*)&x2g[((size_t)i * 512 + j0 + mi * 16 + l15) * 128 + koff];
      f16x8 A1 = *(const f16x8*)&x1[(mi * 16 + l15) * 136 + koff];
      accO[mi][0] = MFMA(A2, B0, accO[mi][0]);
      accO[mi][1] = MFMA(A2, B1, accO[mi][1]);
      accG[mi][0] = MFMA(A1, G0, accG[mi][0]);
      accG[mi][1] = MFMA(A1, G1, accG[mi][1]);
    }
  }
  #pragma unroll
  for (int mi = 0; mi < 4; ++mi){
    #pragma unroll
    for (int r = 0; r < 4; ++r){
      int m = mi * 16 + l4 * 4 + r;
      size_t tok = (size_t)i * 512 + j0 + m;
      #pragma unroll
      for (int nj = 0; nj < 2; ++nj){
        int cout = n0 + nj * 16 + l15;
        out[tok * 128 + cout] = accO[mi][nj][r] * sigm(accG[mi][nj][r]);
      }
    }
  }
}

extern "C" void kernel_launch(void* const* d_in, const int* in_sizes, int n_in,
                              void* d_out, int out_size, void* d_ws, size_t ws_size,
                              hipStream_t stream){
  (void)in_sizes; (void)n_in; (void)out_size; (void)ws_size;
  const float* pair = (const float*)d_in[0];
  const float* mask = (const float*)d_in[1];
  const float* ln1w = (const float*)d_in[2];
  const float* ln1b = (const float*)d_in[3];
  const float* ln2w = (const float*)d_in[4];
  const float* ln2b = (const float*)d_in[5];
  const float* Wp   = (const float*)d_in[6];
  const float* Wg   = (const float*)d_in[7];
  const float* Wo   = (const float*)d_in[8];   // W_out comes BEFORE W_glin in dict order
  const float* Wgl  = (const float*)d_in[9];
  float* out = (float*)d_out;

  // Workspace: exactly 256 MiB.
  //   x2g aliases a_r (dead after k2; k1 fully rewrites a_r every call).
  //   Wc  aliases the head of o_f: k0 writes it, k1 reads it, k2 then overwrites
  //   o_f (k1 already complete). Deterministic on every call.
  char* ws = (char*)d_ws;
  u16*   a_r = (u16*)(ws);                       // 67108864 B   a_r[c][j][k]  fp16
  u16*   b_r = (u16*)(ws + 67108864);            // 67108864 B   b_r[c][i][k]  fp16
  float* o_f = (float*)(ws + 134217728);         // 134217728 B  o_f[c][i][j]  fp32
  u16*   Wc  = (u16*)(ws + 134217728);           // 131072 B    [Wproj;Wgate] fp16 (aliases o_f head)
  u16*   x2g = (u16*)(ws);                       // 67108864 B   x2g[t][ci]    fp16 (aliases a_r)

  hipLaunchKernelGGL(k0_prep,    dim3(256),  dim3(256), 0, stream, Wp, Wg, Wc);
  hipLaunchKernelGGL(k1_ln_proj, dim3(2048), dim3(256), 0, stream, pair, mask, ln1w, ln1b, Wc, a_r, b_r);
  hipLaunchKernelGGL(k2_tri,     dim3(2048), dim3(256), 0, stream, a_r, b_r, o_f);
  hipLaunchKernelGGL(k2b_lnt,    dim3(4096), dim3(256), 0, stream, o_f, ln2w, ln2b, x2g);
  hipLaunchKernelGGL(k3_out,     dim3(4096), dim3(256), 0, stream, x2g, pair, ln1w, ln1b, Wgl, Wo, out);
}